// Round 1
// baseline (831.669 us; speedup 1.0000x reference)
//
#include <hip/hip_runtime.h>

// Problem constants (from reference)
#define NE    8
#define KDIM  2048
#define NDIM  5632
#define NTOK  4096
#define CAP   512      // tokens per expert (balanced routing, = NTOK/NE)
#define NGRP  32       // KDIM / GROUP_SIZE(64)
#define BM    128
#define BN    128
#define BK    32
#define MT    4        // CAP / BM
#define NT    44       // NDIM / BN
#define LDSS  40       // padded LDS row stride (old path)

#define K8      (KDIM / 8)                                  // 256 packed octet-rows
#define NBLK_N  (NDIM / 256)                                // 22
#define PACK_BLOCKS (NE * K8 * NBLK_N)                      // 45056
#define ACV_BLOCKS  (NTOK * KDIM / (8 * 256))               // 4096
#define PACKED_BYTES ((size_t)NE * K8 * NDIM * 4)           // 46,137,344
#define ABF_BYTES    ((size_t)NTOK * KDIM * 2)              // 16,777,216
#define WBT_BYTES    ((size_t)NE * NDIM * KDIM * 2)         // 184,549,376

// dequant-transpose pass geometry: 64 k (one scale group) x 256 n per block
#define KB_DQ (KDIM / 64)                                   // 32
#define NB_DQ (NDIM / 256)                                  // 22
#define DQT_BLOCKS (NE * KB_DQ * NB_DQ)                     // 5632

typedef __attribute__((ext_vector_type(8))) short bf16x8;
typedef __attribute__((ext_vector_type(4))) short bf16x4;
typedef __attribute__((ext_vector_type(4))) float f32x4;

// fp32 -> bf16 round-to-nearest-even (finite inputs only)
static __device__ __forceinline__ short f2bf(float f) {
    union { float f; unsigned u; } x; x.f = f;
    unsigned r = (x.u + 0x7fffu + ((x.u >> 16) & 1u)) >> 16;
    return (short)r;
}

// async global->LDS, 16B per lane. LDS dest must be wave-uniform base + lane*16.
static __device__ __forceinline__ void gl2lds16(const unsigned short* g, short* l) {
    __builtin_amdgcn_global_load_lds(
        (const __attribute__((address_space(1))) unsigned int*)g,
        (__attribute__((address_space(3))) unsigned int*)l, 16, 0, 0);
}

// ---------------- Pass 1 (new): dequant int32 codes -> bf16 B^T [E][N][K]; A -> bf16 ----
// Reads are coalesced across lanes (n contiguous); each thread owns one n column and
// 64 k values = exactly one scale group, so s/z are loaded once per thread.
// Writes are 128 B contiguous per thread along k.
__global__ __launch_bounds__(256)
void dq_kernel(const int* __restrict__ wq, const float* __restrict__ sz,
               const float* __restrict__ inp,
               unsigned short* __restrict__ wbt, unsigned short* __restrict__ abf)
{
    const int bid = blockIdx.x;
    if (bid < DQT_BLOCKS) {
        const int e  = bid / (KB_DQ * NB_DQ);
        const int r  = bid % (KB_DQ * NB_DQ);
        const int kb = r / NB_DQ;
        const int nb = r % NB_DQ;
        const int n  = nb * 256 + threadIdx.x;

        const int* src = wq + ((size_t)e * KDIM + kb * 64) * NDIM + n;
        const float2 s2 = *(const float2*)(sz + (((size_t)e * NGRP + kb) * NDIM + n) * 2);
        const float s  = s2.x;
        const float z8 = s2.y - 8.f * s2.x;            // w = q*s + (z - 8s)
        unsigned short* dst = wbt + ((size_t)e * NDIM + n) * KDIM + kb * 64;

        #pragma unroll
        for (int o = 0; o < 8; ++o) {
            bf16x8 h;
            #pragma unroll
            for (int j = 0; j < 8; ++j) {
                const float q = (float)src[(size_t)(o * 8 + j) * NDIM];
                h[j] = f2bf(fmaf(q, s, z8));
            }
            *(bf16x8*)(dst + o * 8) = h;
        }
    } else {
        // A fp32 -> bf16, 8 elems/thread
        const size_t t = (size_t)(bid - DQT_BLOCKS) * 256 + threadIdx.x;
        const float4* p = (const float4*)inp + t * 2;
        const float4 v0 = p[0], v1 = p[1];
        bf16x8 h;
        h[0] = f2bf(v0.x); h[1] = f2bf(v0.y); h[2] = f2bf(v0.z); h[3] = f2bf(v0.w);
        h[4] = f2bf(v1.x); h[5] = f2bf(v1.y); h[6] = f2bf(v1.z); h[7] = f2bf(v1.w);
        *((bf16x8*)abf + t) = h;
    }
}

// ---------------- Pass 2 (new): clean bf16 grouped GEMM, m97 structure ----------------
// 128x128 tile, BK=32, linear LDS, global_load_lds x16 for BOTH operands.
// e = bid % 8 pins each expert to one XCD (round-robin dispatch): A panel (4 MB)
// stays resident in that XCD's L2; B panels get 4x mt-reuse via L2/LLC.
__global__ __launch_bounds__(256)
void hqq_gemm3(const unsigned short* __restrict__ abf,
               const unsigned short* __restrict__ wbt,
               float* __restrict__ out)
{
    const int bid = blockIdx.x;
    const int e   = bid & 7;
    const int rem = bid >> 3;      // 0..175
    const int nt  = rem >> 2;      // 0..43
    const int mt  = rem & 3;

    __shared__ __align__(16) short Alds[BM * BK];   // [m][k] bf16, linear (for global_load_lds)
    __shared__ __align__(16) short Blds[BN * BK];   // [n][k] bf16, linear

    const int tid = threadIdx.x;
    const int m0  = e * CAP + mt * BM;
    const int n0  = nt * BN;

    const unsigned short* Ab = abf + (size_t)m0 * KDIM;
    const unsigned short* Bb = wbt + ((size_t)e * NDIM + n0) * KDIM;

    f32x4 acc[4][4];
    #pragma unroll
    for (int i = 0; i < 4; ++i)
        #pragma unroll
        for (int j = 0; j < 4; ++j)
            acc[i][j] = (f32x4){0.f, 0.f, 0.f, 0.f};

    const int wave = tid >> 6;
    const int lane = tid & 63;
    const int wm = (wave >> 1) << 6;
    const int wn = (wave & 1) << 6;
    const int lr = lane & 15;
    const int lq = lane >> 4;

    for (int k0 = 0; k0 < KDIM; k0 += BK) {
        // ---- stage: 2x A + 2x B async 16B/lane direct-to-LDS ----
        #pragma unroll
        for (int p = 0; p < 2; ++p) {
            const int idx = p * 256 + tid;        // 0..511
            const int row = idx >> 2;             // 0..127
            const int kq  = idx & 3;              // 16B octet within BK=32
            gl2lds16(Ab + (size_t)row * KDIM + k0 + kq * 8, &Alds[idx * 8]);
            gl2lds16(Bb + (size_t)row * KDIM + k0 + kq * 8, &Blds[idx * 8]);
        }
        __syncthreads();   // drains vmcnt(0): LDS tiles complete

        // ---- compute: 8 ds_read_b128 + 16 MFMA per wave ----
        bf16x8 af[4], bv[4];
        #pragma unroll
        for (int i = 0; i < 4; ++i)
            af[i] = *(const bf16x8*)&Alds[(wm + i * 16 + lr) * BK + lq * 8];
        #pragma unroll
        for (int j = 0; j < 4; ++j)
            bv[j] = *(const bf16x8*)&Blds[(wn + j * 16 + lr) * BK + lq * 8];
        #pragma unroll
        for (int i = 0; i < 4; ++i)
            #pragma unroll
            for (int j = 0; j < 4; ++j)
                acc[i][j] = __builtin_amdgcn_mfma_f32_16x16x32_bf16(af[i], bv[j], acc[i][j], 0, 0, 0);

        __syncthreads();
    }

    const int orow0 = m0 + wm + lq * 4;
    const int ocol0 = n0 + wn + lr;
    #pragma unroll
    for (int i = 0; i < 4; ++i)
        #pragma unroll
        for (int r = 0; r < 4; ++r) {
            float* op = out + (size_t)(orow0 + i * 16 + r) * NDIM + ocol0;
            #pragma unroll
            for (int j = 0; j < 4; ++j)
                op[j * 16] = acc[i][j][r];
        }
}

// ---------------- Old pass 1: pack nibbles (kept as mid-tier fallback) ----------------
__global__ __launch_bounds__(256)
void pack_kernel(const int* __restrict__ wq, const float* __restrict__ inp,
                 unsigned* __restrict__ pw, unsigned short* __restrict__ abf)
{
    const int bid = blockIdx.x;
    if (bid < PACK_BLOCKS) {
        const int e  = bid / (K8 * NBLK_N);
        const int r  = bid % (K8 * NBLK_N);
        const int k8 = r / NBLK_N;
        const int nb = r % NBLK_N;
        const int n  = nb * 256 + threadIdx.x;
        const int* src = wq + ((size_t)e * KDIM + k8 * 8) * NDIM + n;
        unsigned v = 0;
        #pragma unroll
        for (int j = 0; j < 8; ++j)
            v |= (unsigned)(src[(size_t)j * NDIM] & 15) << (4 * j);
        pw[((size_t)e * K8 + k8) * NDIM + n] = v;
    } else {
        const size_t t = (size_t)(bid - PACK_BLOCKS) * 256 + threadIdx.x;
        const float4* p = (const float4*)inp + t * 2;
        const float4 v0 = p[0], v1 = p[1];
        bf16x8 h;
        h[0] = f2bf(v0.x); h[1] = f2bf(v0.y); h[2] = f2bf(v0.z); h[3] = f2bf(v0.w);
        h[4] = f2bf(v1.x); h[5] = f2bf(v1.y); h[6] = f2bf(v1.z); h[7] = f2bf(v1.w);
        *((bf16x8*)abf + t) = h;
    }
}

// ---------------- Old pass 2: fused dequant GEMM (mid-tier fallback) ----------------
__global__ __launch_bounds__(256, 2)
void hqq_gemm2(const unsigned short* __restrict__ abf,
               const unsigned*       __restrict__ pw,
               const float*          __restrict__ sz,
               float*                __restrict__ out)
{
    const int bid = blockIdx.x;
    const int e   = bid / (MT * NT);
    const int rem = bid % (MT * NT);
    const int nt  = rem >> 2;
    const int mt  = rem & 3;

    __shared__ __align__(16) short Alds[BM * LDSS];
    __shared__ __align__(16) short Blds[BN * LDSS];

    const int tid = threadIdx.x;
    const int m0  = e * CAP + mt * BM;
    const int n0  = nt * BN;

    const int a_kq  = tid & 3;
    const int a_row = tid >> 2;
    const int b_n   = tid & 127;
    const int b_h   = tid >> 7;

    const unsigned short* Ab = abf + (size_t)m0 * KDIM;
    const unsigned*       Wb = pw  + (size_t)e * K8 * NDIM + n0 + b_n;
    const float*          SZb = sz + (size_t)e * NGRP * (NDIM * 2) + (size_t)(n0 + b_n) * 2;

    f32x4 acc[4][4];
    #pragma unroll
    for (int i = 0; i < 4; ++i)
        #pragma unroll
        for (int j = 0; j < 4; ++j)
            acc[i][j] = (f32x4){0.f, 0.f, 0.f, 0.f};

    const int wave = tid >> 6;
    const int lane = tid & 63;
    const int wm = (wave >> 1) << 6;
    const int wn = (wave & 1) << 6;
    const int lr = lane & 15;
    const int lq = lane >> 4;

    for (int k0 = 0; k0 < KDIM; k0 += BK) {
        const int g = k0 >> 6;
        #pragma unroll
        for (int p = 0; p < 2; ++p) {
            const int row = a_row + p * 64;
            const bf16x8 v = *(const bf16x8*)(Ab + (size_t)row * KDIM + k0 + a_kq * 8);
            *(bf16x8*)&Alds[row * LDSS + a_kq * 8] = v;
        }
        const float2 s2 = *(const float2*)(SZb + (size_t)g * (NDIM * 2));
        const float s  = s2.x;
        const float z8 = s2.y - 8.f * s2.x;
        const unsigned* wp = Wb + ((size_t)(k0 >> 3) + b_h * 2) * NDIM;
        const unsigned u0 = wp[0];
        const unsigned u1 = wp[NDIM];
        bf16x8 bb0, bb1;
        #pragma unroll
        for (int j = 0; j < 8; ++j) {
            bb0[j] = f2bf(fmaf((float)((u0 >> (4 * j)) & 15u), s, z8));
            bb1[j] = f2bf(fmaf((float)((u1 >> (4 * j)) & 15u), s, z8));
        }
        *(bf16x8*)&Blds[b_n * LDSS + b_h * 16]     = bb0;
        *(bf16x8*)&Blds[b_n * LDSS + b_h * 16 + 8] = bb1;

        __syncthreads();

        bf16x8 af[4], bfv[4];
        #pragma unroll
        for (int i = 0; i < 4; ++i)
            af[i] = *(const bf16x8*)&Alds[(wm + i * 16 + lr) * LDSS + lq * 8];
        #pragma unroll
        for (int j = 0; j < 4; ++j)
            bfv[j] = *(const bf16x8*)&Blds[(wn + j * 16 + lr) * LDSS + lq * 8];
        #pragma unroll
        for (int i = 0; i < 4; ++i)
            #pragma unroll
            for (int j = 0; j < 4; ++j)
                acc[i][j] = __builtin_amdgcn_mfma_f32_16x16x32_bf16(af[i], bfv[j], acc[i][j], 0, 0, 0);

        __syncthreads();
    }

    const int orow0 = m0 + wm + lq * 4;
    const int ocol0 = n0 + wn + lr;
    #pragma unroll
    for (int i = 0; i < 4; ++i)
        #pragma unroll
        for (int r = 0; r < 4; ++r) {
            float* op = out + (size_t)(orow0 + i * 16 + r) * NDIM + ocol0;
            #pragma unroll
            for (int j = 0; j < 4; ++j)
                op[j * 16] = acc[i][j][r];
        }
}

// ---------------- Fallback (no workspace) ----------------
__global__ __launch_bounds__(256, 2)
void hqq_gemm_fallback(const float* __restrict__ inp,
                       const int*   __restrict__ wq,
                       const float* __restrict__ sz,
                       float*       __restrict__ out)
{
    const int bid = blockIdx.x;
    const int e   = bid / (MT * NT);
    const int rem = bid % (MT * NT);
    const int nt  = rem >> 2;
    const int mt  = rem & 3;

    __shared__ __align__(16) short Alds[BM * LDSS];
    __shared__ __align__(16) short Blds[BN * LDSS];

    const int tid = threadIdx.x;
    const int m0  = e * CAP + mt * BM;
    const int n0  = nt * BN;

    const int a_kq  = tid & 7;
    const int a_row = tid >> 3;
    const int b_n   = tid & 127;
    const int b_h   = tid >> 7;

    const float* Ab  = inp + (size_t)m0 * KDIM;
    const int*   Wb  = wq  + (size_t)e * KDIM * NDIM + n0 + b_n;
    const float* SZb = sz  + (size_t)e * NGRP * (NDIM * 2) + (size_t)(n0 + b_n) * 2;

    f32x4 acc[4][4];
    #pragma unroll
    for (int i = 0; i < 4; ++i)
        #pragma unroll
        for (int j = 0; j < 4; ++j)
            acc[i][j] = (f32x4){0.f, 0.f, 0.f, 0.f};

    const int wave = tid >> 6;
    const int lane = tid & 63;
    const int wm = (wave >> 1) << 6;
    const int wn = (wave & 1) << 6;
    const int lr = lane & 15;
    const int lq = lane >> 4;

    for (int k0 = 0; k0 < KDIM; k0 += BK) {
        const int g = k0 >> 6;
        #pragma unroll
        for (int p = 0; p < 4; ++p) {
            const int row = a_row + p * 32;
            const float4 v = *(const float4*)(Ab + (size_t)row * KDIM + k0 + a_kq * 4);
            bf16x4 h;
            h[0] = f2bf(v.x); h[1] = f2bf(v.y); h[2] = f2bf(v.z); h[3] = f2bf(v.w);
            *(bf16x4*)&Alds[row * LDSS + a_kq * 4] = h;
        }
        const float2 s2 = *(const float2*)(SZb + (size_t)g * (NDIM * 2));
        const float s  = s2.x;
        const float z8 = s2.y - 8.f * s2.x;
        #pragma unroll
        for (int oo = 0; oo < 2; ++oo) {
            const int ko = b_h * 8 + oo * 16;
            const int* wp = Wb + (size_t)(k0 + ko) * NDIM;
            bf16x8 bb;
            #pragma unroll
            for (int j = 0; j < 8; ++j) {
                const float q = (float)wp[(size_t)j * NDIM];
                bb[j] = f2bf(fmaf(q, s, z8));
            }
            *(bf16x8*)&Blds[b_n * LDSS + ko] = bb;
        }
        __syncthreads();
        bf16x8 af[4], bfv[4];
        #pragma unroll
        for (int i = 0; i < 4; ++i)
            af[i] = *(const bf16x8*)&Alds[(wm + i * 16 + lr) * LDSS + lq * 8];
        #pragma unroll
        for (int j = 0; j < 4; ++j)
            bfv[j] = *(const bf16x8*)&Blds[(wn + j * 16 + lr) * LDSS + lq * 8];
        #pragma unroll
        for (int i = 0; i < 4; ++i)
            #pragma unroll
            for (int j = 0; j < 4; ++j)
                acc[i][j] = __builtin_amdgcn_mfma_f32_16x16x32_bf16(af[i], bfv[j], acc[i][j], 0, 0, 0);
        __syncthreads();
    }

    const int orow0 = m0 + wm + lq * 4;
    const int ocol0 = n0 + wn + lr;
    #pragma unroll
    for (int i = 0; i < 4; ++i)
        #pragma unroll
        for (int r = 0; r < 4; ++r) {
            float* op = out + (size_t)(orow0 + i * 16 + r) * NDIM + ocol0;
            #pragma unroll
            for (int j = 0; j < 4; ++j)
                op[j * 16] = acc[i][j][r];
        }
}

extern "C" void kernel_launch(void* const* d_in, const int* in_sizes, int n_in,
                              void* d_out, int out_size, void* d_ws, size_t ws_size,
                              hipStream_t stream) {
    const float* inp = (const float*)d_in[0];
    const int*   wq  = (const int*)d_in[2];
    const float* sz  = (const float*)d_in[3];
    float*       out = (float*)d_out;

    if (ws_size >= ABF_BYTES + WBT_BYTES) {
        // Best path: dequant-to-bf16 pass + clean bf16 GEMM with global_load_lds
        unsigned short* abf = (unsigned short*)d_ws;
        unsigned short* wbt = (unsigned short*)((char*)d_ws + ABF_BYTES);
        dq_kernel<<<dim3(DQT_BLOCKS + ACV_BLOCKS), dim3(256), 0, stream>>>(wq, sz, inp, wbt, abf);
        hqq_gemm3<<<dim3(NE * MT * NT), dim3(256), 0, stream>>>(abf, wbt, out);
    } else if (ws_size >= PACKED_BYTES + ABF_BYTES) {
        unsigned*       pw  = (unsigned*)d_ws;
        unsigned short* abf = (unsigned short*)((char*)d_ws + PACKED_BYTES);
        pack_kernel<<<dim3(PACK_BLOCKS + ACV_BLOCKS), dim3(256), 0, stream>>>(wq, inp, pw, abf);
        hqq_gemm2<<<dim3(NE * MT * NT), dim3(256), 0, stream>>>(abf, pw, sz, out);
    } else {
        hqq_gemm_fallback<<<dim3(NE * MT * NT), dim3(256), 0, stream>>>(inp, wq, sz, out);
    }
}

// Round 3
// 738.118 us; speedup vs baseline: 1.1267x; 1.1267x over previous
//
#include <hip/hip_runtime.h>

// Problem constants (from reference)
#define NE    8
#define KDIM  2048
#define NDIM  5632
#define NTOK  4096
#define CAP   512      // tokens per expert (balanced routing, = NTOK/NE)
#define NGRP  32       // KDIM / GROUP_SIZE(64)
#define BM    128
#define BN    128
#define BK    32
#define MT    4        // CAP / BM
#define NT    44       // NDIM / BN
#define LDSS  40       // padded LDS row stride (old path)

#define K8      (KDIM / 8)                                  // 256 packed octet-rows
#define NBLK_N  (NDIM / 256)                                // 22
#define PACK_BLOCKS (NE * K8 * NBLK_N)                      // 45056
#define ACV_BLOCKS  (NTOK * KDIM / (8 * 256))               // 4096
#define PACKED_BYTES ((size_t)NE * K8 * NDIM * 4)           // 46,137,344
#define ABF_BYTES    ((size_t)NTOK * KDIM * 2)              // 16,777,216
#define WBT_BYTES    ((size_t)NE * NDIM * KDIM * 2)         // 184,549,376

// dequant-transpose pass geometry: [128 k x 128 n] tile per block
#define KT_DQ (KDIM / 128)                                  // 16
#define NT_DQ (NDIM / 128)                                  // 44
#define DQT_BLOCKS (NE * KT_DQ * NT_DQ)                     // 5632

typedef __attribute__((ext_vector_type(8))) short bf16x8;
typedef __attribute__((ext_vector_type(4))) short bf16x4;
typedef __attribute__((ext_vector_type(4))) float f32x4;

// fp32 -> bf16 round-to-nearest-even (finite inputs only)
static __device__ __forceinline__ short f2bf(float f) {
    union { float f; unsigned u; } x; x.f = f;
    unsigned r = (x.u + 0x7fffu + ((x.u >> 16) & 1u)) >> 16;
    return (short)r;
}

// async global->LDS, 16B per lane. LDS dest must be wave-uniform base + lane*16.
static __device__ __forceinline__ void gl2lds16(const unsigned short* g, short* l) {
    __builtin_amdgcn_global_load_lds(
        (const __attribute__((address_space(1))) unsigned int*)g,
        (__attribute__((address_space(3))) unsigned int*)l, 16, 0, 0);
}

// ---------------- Pass 1: dequant int32 codes -> bf16 B^T [E][N][K] via LDS transpose ----
// Reads:  [128k x 128n] int tile; per wave-instr 2 rows x 512 B contiguous (full lines).
// Writes: per wave-instr 8 n-rows x 128 B contiguous runs (full lines) -> no write amp.
// LDS: [n][k] bf16 tile, 16B slots XOR-swizzled by (n&15) for bank spread both phases.
__global__ __launch_bounds__(256)
void dq_kernel(const int* __restrict__ wq, const float* __restrict__ sz,
               const float* __restrict__ inp,
               unsigned short* __restrict__ wbt, unsigned short* __restrict__ abf)
{
    const int bid = blockIdx.x;
    if (bid < DQT_BLOCKS) {
        const int e  = bid / (KT_DQ * NT_DQ);
        const int r  = bid % (KT_DQ * NT_DQ);
        const int kt = r / NT_DQ;
        const int ntb = r % NT_DQ;
        const int k0 = kt * 128;
        const int n0 = ntb * 128;
        const int t  = threadIdx.x;

        __shared__ __align__(16) short T[128 * 128];   // 32 KB

        // ---- read phase: thread owns 4 ints (n) x 16 rows (k) ----
        const int col  = t & 31;          // 16B column: ints [col*4, col*4+4)
        const int band = t >> 5;          // 0..7 -> rows band*16 .. band*16+15
        const int g    = (k0 >> 6) + (band >> 2);   // scale group (uniform per thread)

        float s_[4], z_[4];
        #pragma unroll
        for (int j = 0; j < 4; ++j) {
            const int n = n0 + col * 4 + j;
            const float2 s2 = *(const float2*)(sz + (((size_t)e * NGRP + g) * NDIM + n) * 2);
            s_[j] = s2.x;
            z_[j] = s2.y - 8.f * s2.x;    // w = q*s + (z - 8s)
        }

        const int* src = wq + ((size_t)e * KDIM + k0 + band * 16) * NDIM + n0 + col * 4;

        #pragma unroll
        for (int p4 = 0; p4 < 4; ++p4) {
            // 4 consecutive k-rows, 4 n each -> 4x4 micro-transpose
            int4 v0 = *(const int4*)(src + (size_t)(p4 * 4 + 0) * NDIM);
            int4 v1 = *(const int4*)(src + (size_t)(p4 * 4 + 1) * NDIM);
            int4 v2 = *(const int4*)(src + (size_t)(p4 * 4 + 2) * NDIM);
            int4 v3 = *(const int4*)(src + (size_t)(p4 * 4 + 3) * NDIM);
            const int kb = band * 16 + p4 * 4;
            const int slotbase = kb >> 3;          // 16B slot of this quad
            const int halfoff  = (kb & 7);         // 0 or 4 shorts within slot

            #pragma unroll
            for (int j = 0; j < 4; ++j) {
                const int q0 = (j == 0) ? v0.x : (j == 1) ? v0.y : (j == 2) ? v0.z : v0.w;
                const int q1 = (j == 0) ? v1.x : (j == 1) ? v1.y : (j == 2) ? v1.z : v1.w;
                const int q2 = (j == 0) ? v2.x : (j == 1) ? v2.y : (j == 2) ? v2.z : v2.w;
                const int q3 = (j == 0) ? v3.x : (j == 1) ? v3.y : (j == 2) ? v3.z : v3.w;
                bf16x4 quad;
                quad[0] = f2bf(fmaf((float)q0, s_[j], z_[j]));
                quad[1] = f2bf(fmaf((float)q1, s_[j], z_[j]));
                quad[2] = f2bf(fmaf((float)q2, s_[j], z_[j]));
                quad[3] = f2bf(fmaf((float)q3, s_[j], z_[j]));
                const int n_l = col * 4 + j;
                const int addr = n_l * 128 + ((slotbase ^ (n_l & 15)) << 3) + halfoff;
                *(bf16x4*)&T[addr] = quad;
            }
        }

        __syncthreads();

        // ---- write phase: 8 lanes per n-row -> 128B contiguous runs ----
        const int wc = t & 7;             // slot within half-row
        const int wn = t >> 3;            // 0..31
        #pragma unroll
        for (int p = 0; p < 4; ++p) {
            const int n_l = wn + p * 32;
            const int x = n_l & 15;
            unsigned short* dst = wbt + ((size_t)e * NDIM + n0 + n_l) * KDIM + k0;
            const bf16x8 r0 = *(const bf16x8*)&T[n_l * 128 + ((wc ^ x) << 3)];
            const bf16x8 r1 = *(const bf16x8*)&T[n_l * 128 + (((wc + 8) ^ x) << 3)];
            *(bf16x8*)(dst + wc * 8) = r0;
            *(bf16x8*)(dst + (wc + 8) * 8) = r1;
        }
    } else {
        // A fp32 -> bf16, 8 elems/thread
        const size_t t = (size_t)(bid - DQT_BLOCKS) * 256 + threadIdx.x;
        const float4* p = (const float4*)inp + t * 2;
        const float4 v0 = p[0], v1 = p[1];
        bf16x8 h;
        h[0] = f2bf(v0.x); h[1] = f2bf(v0.y); h[2] = f2bf(v0.z); h[3] = f2bf(v0.w);
        h[4] = f2bf(v1.x); h[5] = f2bf(v1.y); h[6] = f2bf(v1.z); h[7] = f2bf(v1.w);
        *((bf16x8*)abf + t) = h;
    }
}

// ---------------- Pass 2: clean bf16 grouped GEMM, m97 structure ----------------
__global__ __launch_bounds__(256)
void hqq_gemm3(const unsigned short* __restrict__ abf,
               const unsigned short* __restrict__ wbt,
               float* __restrict__ out)
{
    const int bid = blockIdx.x;
    const int e   = bid & 7;
    const int rem = bid >> 3;      // 0..175
    const int nt  = rem >> 2;      // 0..43
    const int mt  = rem & 3;

    __shared__ __align__(16) short Alds[BM * BK];   // [m][k] bf16, linear (for global_load_lds)
    __shared__ __align__(16) short Blds[BN * BK];   // [n][k] bf16, linear

    const int tid = threadIdx.x;
    const int m0  = e * CAP + mt * BM;
    const int n0  = nt * BN;

    const unsigned short* Ab = abf + (size_t)m0 * KDIM;
    const unsigned short* Bb = wbt + ((size_t)e * NDIM + n0) * KDIM;

    f32x4 acc[4][4];
    #pragma unroll
    for (int i = 0; i < 4; ++i)
        #pragma unroll
        for (int j = 0; j < 4; ++j)
            acc[i][j] = (f32x4){0.f, 0.f, 0.f, 0.f};

    const int wave = tid >> 6;
    const int lane = tid & 63;
    const int wm = (wave >> 1) << 6;
    const int wn = (wave & 1) << 6;
    const int lr = lane & 15;
    const int lq = lane >> 4;

    for (int k0 = 0; k0 < KDIM; k0 += BK) {
        #pragma unroll
        for (int p = 0; p < 2; ++p) {
            const int idx = p * 256 + tid;        // 0..511
            const int row = idx >> 2;             // 0..127
            const int kq  = idx & 3;              // 16B octet within BK=32
            gl2lds16(Ab + (size_t)row * KDIM + k0 + kq * 8, &Alds[idx * 8]);
            gl2lds16(Bb + (size_t)row * KDIM + k0 + kq * 8, &Blds[idx * 8]);
        }
        __syncthreads();

        bf16x8 af[4], bv[4];
        #pragma unroll
        for (int i = 0; i < 4; ++i)
            af[i] = *(const bf16x8*)&Alds[(wm + i * 16 + lr) * BK + lq * 8];
        #pragma unroll
        for (int j = 0; j < 4; ++j)
            bv[j] = *(const bf16x8*)&Blds[(wn + j * 16 + lr) * BK + lq * 8];
        #pragma unroll
        for (int i = 0; i < 4; ++i)
            #pragma unroll
            for (int j = 0; j < 4; ++j)
                acc[i][j] = __builtin_amdgcn_mfma_f32_16x16x32_bf16(af[i], bv[j], acc[i][j], 0, 0, 0);

        __syncthreads();
    }

    const int orow0 = m0 + wm + lq * 4;
    const int ocol0 = n0 + wn + lr;
    #pragma unroll
    for (int i = 0; i < 4; ++i)
        #pragma unroll
        for (int r = 0; r < 4; ++r) {
            float* op = out + (size_t)(orow0 + i * 16 + r) * NDIM + ocol0;
            #pragma unroll
            for (int j = 0; j < 4; ++j)
                op[j * 16] = acc[i][j][r];
        }
}

// ---------------- Old pass 1: pack nibbles (mid-tier fallback) ----------------
__global__ __launch_bounds__(256)
void pack_kernel(const int* __restrict__ wq, const float* __restrict__ inp,
                 unsigned* __restrict__ pw, unsigned short* __restrict__ abf)
{
    const int bid = blockIdx.x;
    if (bid < PACK_BLOCKS) {
        const int e  = bid / (K8 * NBLK_N);
        const int r  = bid % (K8 * NBLK_N);
        const int k8 = r / NBLK_N;
        const int nb = r % NBLK_N;
        const int n  = nb * 256 + threadIdx.x;
        const int* src = wq + ((size_t)e * KDIM + k8 * 8) * NDIM + n;
        unsigned v = 0;
        #pragma unroll
        for (int j = 0; j < 8; ++j)
            v |= (unsigned)(src[(size_t)j * NDIM] & 15) << (4 * j);
        pw[((size_t)e * K8 + k8) * NDIM + n] = v;
    } else {
        const size_t t = (size_t)(bid - PACK_BLOCKS) * 256 + threadIdx.x;
        const float4* p = (const float4*)inp + t * 2;
        const float4 v0 = p[0], v1 = p[1];
        bf16x8 h;
        h[0] = f2bf(v0.x); h[1] = f2bf(v0.y); h[2] = f2bf(v0.z); h[3] = f2bf(v0.w);
        h[4] = f2bf(v1.x); h[5] = f2bf(v1.y); h[6] = f2bf(v1.z); h[7] = f2bf(v1.w);
        *((bf16x8*)abf + t) = h;
    }
}

// ---------------- Old pass 2: fused dequant GEMM (mid-tier fallback) ----------------
__global__ __launch_bounds__(256, 2)
void hqq_gemm2(const unsigned short* __restrict__ abf,
               const unsigned*       __restrict__ pw,
               const float*          __restrict__ sz,
               float*                __restrict__ out)
{
    const int bid = blockIdx.x;
    const int e   = bid / (MT * NT);
    const int rem = bid % (MT * NT);
    const int nt  = rem >> 2;
    const int mt  = rem & 3;

    __shared__ __align__(16) short Alds[BM * LDSS];
    __shared__ __align__(16) short Blds[BN * LDSS];

    const int tid = threadIdx.x;
    const int m0  = e * CAP + mt * BM;
    const int n0  = nt * BN;

    const int a_kq  = tid & 3;
    const int a_row = tid >> 2;
    const int b_n   = tid & 127;
    const int b_h   = tid >> 7;

    const unsigned short* Ab = abf + (size_t)m0 * KDIM;
    const unsigned*       Wb = pw  + (size_t)e * K8 * NDIM + n0 + b_n;
    const float*          SZb = sz + (size_t)e * NGRP * (NDIM * 2) + (size_t)(n0 + b_n) * 2;

    f32x4 acc[4][4];
    #pragma unroll
    for (int i = 0; i < 4; ++i)
        #pragma unroll
        for (int j = 0; j < 4; ++j)
            acc[i][j] = (f32x4){0.f, 0.f, 0.f, 0.f};

    const int wave = tid >> 6;
    const int lane = tid & 63;
    const int wm = (wave >> 1) << 6;
    const int wn = (wave & 1) << 6;
    const int lr = lane & 15;
    const int lq = lane >> 4;

    for (int k0 = 0; k0 < KDIM; k0 += BK) {
        const int g = k0 >> 6;
        #pragma unroll
        for (int p = 0; p < 2; ++p) {
            const int row = a_row + p * 64;
            const bf16x8 v = *(const bf16x8*)(Ab + (size_t)row * KDIM + k0 + a_kq * 8);
            *(bf16x8*)&Alds[row * LDSS + a_kq * 8] = v;
        }
        const float2 s2 = *(const float2*)(SZb + (size_t)g * (NDIM * 2));
        const float s  = s2.x;
        const float z8 = s2.y - 8.f * s2.x;
        const unsigned* wp = Wb + ((size_t)(k0 >> 3) + b_h * 2) * NDIM;
        const unsigned u0 = wp[0];
        const unsigned u1 = wp[NDIM];
        bf16x8 bb0, bb1;
        #pragma unroll
        for (int j = 0; j < 8; ++j) {
            bb0[j] = f2bf(fmaf((float)((u0 >> (4 * j)) & 15u), s, z8));
            bb1[j] = f2bf(fmaf((float)((u1 >> (4 * j)) & 15u), s, z8));
        }
        *(bf16x8*)&Blds[b_n * LDSS + b_h * 16]     = bb0;
        *(bf16x8*)&Blds[b_n * LDSS + b_h * 16 + 8] = bb1;

        __syncthreads();

        bf16x8 af[4], bfv[4];
        #pragma unroll
        for (int i = 0; i < 4; ++i)
            af[i] = *(const bf16x8*)&Alds[(wm + i * 16 + lr) * LDSS + lq * 8];
        #pragma unroll
        for (int j = 0; j < 4; ++j)
            bfv[j] = *(const bf16x8*)&Blds[(wn + j * 16 + lr) * LDSS + lq * 8];
        #pragma unroll
        for (int i = 0; i < 4; ++i)
            #pragma unroll
            for (int j = 0; j < 4; ++j)
                acc[i][j] = __builtin_amdgcn_mfma_f32_16x16x32_bf16(af[i], bfv[j], acc[i][j], 0, 0, 0);

        __syncthreads();
    }

    const int orow0 = m0 + wm + lq * 4;
    const int ocol0 = n0 + wn + lr;
    #pragma unroll
    for (int i = 0; i < 4; ++i)
        #pragma unroll
        for (int r = 0; r < 4; ++r) {
            float* op = out + (size_t)(orow0 + i * 16 + r) * NDIM + ocol0;
            #pragma unroll
            for (int j = 0; j < 4; ++j)
                op[j * 16] = acc[i][j][r];
        }
}

// ---------------- Fallback (no workspace) ----------------
__global__ __launch_bounds__(256, 2)
void hqq_gemm_fallback(const float* __restrict__ inp,
                       const int*   __restrict__ wq,
                       const float* __restrict__ sz,
                       float*       __restrict__ out)
{
    const int bid = blockIdx.x;
    const int e   = bid / (MT * NT);
    const int rem = bid % (MT * NT);
    const int nt  = rem >> 2;
    const int mt  = rem & 3;

    __shared__ __align__(16) short Alds[BM * LDSS];
    __shared__ __align__(16) short Blds[BN * LDSS];

    const int tid = threadIdx.x;
    const int m0  = e * CAP + mt * BM;
    const int n0  = nt * BN;

    const int a_kq  = tid & 7;
    const int a_row = tid >> 3;
    const int b_n   = tid & 127;
    const int b_h   = tid >> 7;

    const float* Ab  = inp + (size_t)m0 * KDIM;
    const int*   Wb  = wq  + (size_t)e * KDIM * NDIM + n0 + b_n;
    const float* SZb = sz  + (size_t)e * NGRP * (NDIM * 2) + (size_t)(n0 + b_n) * 2;

    f32x4 acc[4][4];
    #pragma unroll
    for (int i = 0; i < 4; ++i)
        #pragma unroll
        for (int j = 0; j < 4; ++j)
            acc[i][j] = (f32x4){0.f, 0.f, 0.f, 0.f};

    const int wave = tid >> 6;
    const int lane = tid & 63;
    const int wm = (wave >> 1) << 6;
    const int wn = (wave & 1) << 6;
    const int lr = lane & 15;
    const int lq = lane >> 4;

    for (int k0 = 0; k0 < KDIM; k0 += BK) {
        const int g = k0 >> 6;
        #pragma unroll
        for (int p = 0; p < 4; ++p) {
            const int row = a_row + p * 32;
            const float4 v = *(const float4*)(Ab + (size_t)row * KDIM + k0 + a_kq * 4);
            bf16x4 h;
            h[0] = f2bf(v.x); h[1] = f2bf(v.y); h[2] = f2bf(v.z); h[3] = f2bf(v.w);
            *(bf16x4*)&Alds[row * LDSS + a_kq * 4] = h;
        }
        const float2 s2 = *(const float2*)(SZb + (size_t)g * (NDIM * 2));
        const float s  = s2.x;
        const float z8 = s2.y - 8.f * s2.x;
        #pragma unroll
        for (int oo = 0; oo < 2; ++oo) {
            const int ko = b_h * 8 + oo * 16;
            const int* wp = Wb + (size_t)(k0 + ko) * NDIM;
            bf16x8 bb;
            #pragma unroll
            for (int j = 0; j < 8; ++j) {
                const float q = (float)wp[(size_t)j * NDIM];
                bb[j] = f2bf(fmaf(q, s, z8));
            }
            *(bf16x8*)&Blds[b_n * LDSS + ko] = bb;
        }
        __syncthreads();
        bf16x8 af[4], bfv[4];
        #pragma unroll
        for (int i = 0; i < 4; ++i)
            af[i] = *(const bf16x8*)&Alds[(wm + i * 16 + lr) * LDSS + lq * 8];
        #pragma unroll
        for (int j = 0; j < 4; ++j)
            bfv[j] = *(const bf16x8*)&Blds[(wn + j * 16 + lr) * LDSS + lq * 8];
        #pragma unroll
        for (int i = 0; i < 4; ++i)
            #pragma unroll
            for (int j = 0; j < 4; ++j)
                acc[i][j] = __builtin_amdgcn_mfma_f32_16x16x32_bf16(af[i], bfv[j], acc[i][j], 0, 0, 0);
        __syncthreads();
    }

    const int orow0 = m0 + wm + lq * 4;
    const int ocol0 = n0 + wn + lr;
    #pragma unroll
    for (int i = 0; i < 4; ++i)
        #pragma unroll
        for (int r = 0; r < 4; ++r) {
            float* op = out + (size_t)(orow0 + i * 16 + r) * NDIM + ocol0;
            #pragma unroll
            for (int j = 0; j < 4; ++j)
                op[j * 16] = acc[i][j][r];
        }
}

extern "C" void kernel_launch(void* const* d_in, const int* in_sizes, int n_in,
                              void* d_out, int out_size, void* d_ws, size_t ws_size,
                              hipStream_t stream) {
    const float* inp = (const float*)d_in[0];
    const int*   wq  = (const int*)d_in[2];
    const float* sz  = (const float*)d_in[3];
    float*       out = (float*)d_out;

    if (ws_size >= ABF_BYTES + WBT_BYTES) {
        unsigned short* abf = (unsigned short*)d_ws;
        unsigned short* wbt = (unsigned short*)((char*)d_ws + ABF_BYTES);
        dq_kernel<<<dim3(DQT_BLOCKS + ACV_BLOCKS), dim3(256), 0, stream>>>(wq, sz, inp, wbt, abf);
        hqq_gemm3<<<dim3(NE * MT * NT), dim3(256), 0, stream>>>(abf, wbt, out);
    } else if (ws_size >= PACKED_BYTES + ABF_BYTES) {
        unsigned*       pw  = (unsigned*)d_ws;
        unsigned short* abf = (unsigned short*)((char*)d_ws + PACKED_BYTES);
        pack_kernel<<<dim3(PACK_BLOCKS + ACV_BLOCKS), dim3(256), 0, stream>>>(wq, inp, pw, abf);
        hqq_gemm2<<<dim3(NE * MT * NT), dim3(256), 0, stream>>>(abf, pw, sz, out);
    } else {
        hqq_gemm_fallback<<<dim3(NE * MT * NT), dim3(256), 0, stream>>>(inp, wq, sz, out);
    }
}

// Round 5
// 699.356 us; speedup vs baseline: 1.1892x; 1.0554x over previous
//
#include <hip/hip_runtime.h>

// Problem constants (from reference)
#define NE    8
#define KDIM  2048
#define NDIM  5632
#define NTOK  4096
#define CAP   512      // tokens per expert (balanced routing, = NTOK/NE)
#define NGRP  32       // KDIM / GROUP_SIZE(64)
#define BM    128
#define BN    128
#define BK    32
#define MT    4        // CAP / BM
#define NT    44       // NDIM / BN
#define LDSS  40       // padded LDS row stride (old path)

#define K8      (KDIM / 8)                                  // 256 packed octet-rows
#define NBLK_N  (NDIM / 256)                                // 22
#define PACK_BLOCKS (NE * K8 * NBLK_N)                      // 45056
#define ACV_BLOCKS  (NTOK * KDIM / (8 * 256))               // 4096
#define PACKED_BYTES ((size_t)NE * K8 * NDIM * 4)           // 46,137,344
#define ABF_BYTES    ((size_t)NTOK * KDIM * 2)              // 16,777,216
#define WBT_BYTES    ((size_t)NE * NDIM * KDIM * 2)         // 184,549,376

// dequant-transpose pass geometry: [128 k x 128 n] tile per block
#define KT_DQ (KDIM / 128)                                  // 16
#define NT_DQ (NDIM / 128)                                  // 44
#define DQT_BLOCKS (NE * KT_DQ * NT_DQ)                     // 5632

typedef __attribute__((ext_vector_type(8))) short bf16x8;
typedef __attribute__((ext_vector_type(4))) short bf16x4;
typedef __attribute__((ext_vector_type(4))) float f32x4;

// fp32 -> bf16 round-to-nearest-even (finite inputs only)
static __device__ __forceinline__ short f2bf(float f) {
    union { float f; unsigned u; } x; x.f = f;
    unsigned r = (x.u + 0x7fffu + ((x.u >> 16) & 1u)) >> 16;
    return (short)r;
}

// async global->LDS, 16B per lane. LDS dest must be wave-uniform base + lane*16.
static __device__ __forceinline__ void gl2lds16(const unsigned short* g, short* l) {
    __builtin_amdgcn_global_load_lds(
        (const __attribute__((address_space(1))) unsigned int*)g,
        (__attribute__((address_space(3))) unsigned int*)l, 16, 0, 0);
}

// ---------------- Pass 1: dequant int32 codes -> bf16 B^T [E][N][K] via LDS transpose ----
// Reads:  [128k x 128n] int tile; per wave-instr 2 rows x 512 B contiguous (full lines).
// Writes: per wave-instr 8 n-rows x 128 B contiguous runs (full lines) -> no write amp.
// LDS: [n][k] bf16 tile, 16B slots XOR-swizzled by (n&15) for bank spread both phases.
__global__ __launch_bounds__(256)
void dq_kernel(const int* __restrict__ wq, const float* __restrict__ sz,
               const float* __restrict__ inp,
               unsigned short* __restrict__ wbt, unsigned short* __restrict__ abf)
{
    const int bid = blockIdx.x;
    if (bid < DQT_BLOCKS) {
        const int e  = bid / (KT_DQ * NT_DQ);
        const int r  = bid % (KT_DQ * NT_DQ);
        const int kt = r / NT_DQ;
        const int ntb = r % NT_DQ;
        const int k0 = kt * 128;
        const int n0 = ntb * 128;
        const int t  = threadIdx.x;

        __shared__ __align__(16) short T[128 * 128];   // 32 KB

        // ---- read phase: thread owns 4 ints (n) x 16 rows (k) ----
        const int col  = t & 31;          // 16B column: ints [col*4, col*4+4)
        const int band = t >> 5;          // 0..7 -> rows band*16 .. band*16+15
        const int g    = (k0 >> 6) + (band >> 2);   // scale group (uniform per thread)

        float s_[4], z_[4];
        #pragma unroll
        for (int j = 0; j < 4; ++j) {
            const int n = n0 + col * 4 + j;
            const float2 s2 = *(const float2*)(sz + (((size_t)e * NGRP + g) * NDIM + n) * 2);
            s_[j] = s2.x;
            z_[j] = s2.y - 8.f * s2.x;    // w = q*s + (z - 8s)
        }

        const int* src = wq + ((size_t)e * KDIM + k0 + band * 16) * NDIM + n0 + col * 4;

        #pragma unroll
        for (int p4 = 0; p4 < 4; ++p4) {
            // 4 consecutive k-rows, 4 n each -> 4x4 micro-transpose
            int4 v0 = *(const int4*)(src + (size_t)(p4 * 4 + 0) * NDIM);
            int4 v1 = *(const int4*)(src + (size_t)(p4 * 4 + 1) * NDIM);
            int4 v2 = *(const int4*)(src + (size_t)(p4 * 4 + 2) * NDIM);
            int4 v3 = *(const int4*)(src + (size_t)(p4 * 4 + 3) * NDIM);
            const int kb = band * 16 + p4 * 4;
            const int slotbase = kb >> 3;          // 16B slot of this quad
            const int halfoff  = (kb & 7);         // 0 or 4 shorts within slot

            #pragma unroll
            for (int j = 0; j < 4; ++j) {
                const int q0 = (j == 0) ? v0.x : (j == 1) ? v0.y : (j == 2) ? v0.z : v0.w;
                const int q1 = (j == 0) ? v1.x : (j == 1) ? v1.y : (j == 2) ? v1.z : v1.w;
                const int q2 = (j == 0) ? v2.x : (j == 1) ? v2.y : (j == 2) ? v2.z : v2.w;
                const int q3 = (j == 0) ? v3.x : (j == 1) ? v3.y : (j == 2) ? v3.z : v3.w;
                bf16x4 quad;
                quad[0] = f2bf(fmaf((float)q0, s_[j], z_[j]));
                quad[1] = f2bf(fmaf((float)q1, s_[j], z_[j]));
                quad[2] = f2bf(fmaf((float)q2, s_[j], z_[j]));
                quad[3] = f2bf(fmaf((float)q3, s_[j], z_[j]));
                const int n_l = col * 4 + j;
                const int addr = n_l * 128 + ((slotbase ^ (n_l & 15)) << 3) + halfoff;
                *(bf16x4*)&T[addr] = quad;
            }
        }

        __syncthreads();

        // ---- write phase: 8 lanes per n-row -> 128B contiguous runs ----
        const int wc = t & 7;             // slot within half-row
        const int wn = t >> 3;            // 0..31
        #pragma unroll
        for (int p = 0; p < 4; ++p) {
            const int n_l = wn + p * 32;
            const int x = n_l & 15;
            unsigned short* dst = wbt + ((size_t)e * NDIM + n0 + n_l) * KDIM + k0;
            const bf16x8 r0 = *(const bf16x8*)&T[n_l * 128 + ((wc ^ x) << 3)];
            const bf16x8 r1 = *(const bf16x8*)&T[n_l * 128 + (((wc + 8) ^ x) << 3)];
            *(bf16x8*)(dst + wc * 8) = r0;
            *(bf16x8*)(dst + (wc + 8) * 8) = r1;
        }
    } else {
        // A fp32 -> bf16, 8 elems/thread
        const size_t t = (size_t)(bid - DQT_BLOCKS) * 256 + threadIdx.x;
        const float4* p = (const float4*)inp + t * 2;
        const float4 v0 = p[0], v1 = p[1];
        bf16x8 h;
        h[0] = f2bf(v0.x); h[1] = f2bf(v0.y); h[2] = f2bf(v0.z); h[3] = f2bf(v0.w);
        h[4] = f2bf(v1.x); h[5] = f2bf(v1.y); h[6] = f2bf(v1.z); h[7] = f2bf(v1.w);
        *((bf16x8*)abf + t) = h;
    }
}

// ---------------- Pass 2: bf16 grouped GEMM, m97 structure + dbuf + occupancy pin ----
// __launch_bounds__(256,3): min 3 waves/EU -> caps VGPR at ~170, guarantees >=3
// blocks/CU (our reg footprint ~130, no spill). Double-buffered LDS, ONE barrier
// per K-step: next-tile global_load_lds issued BEFORE compute, so the barrier's
// implicit vmcnt(0) waits on loads that had the whole compute phase to land.
__global__ __launch_bounds__(256, 3)
void hqq_gemm3(const unsigned short* __restrict__ abf,
               const unsigned short* __restrict__ wbt,
               float* __restrict__ out)
{
    const int bid = blockIdx.x;
    const int e   = bid & 7;       // expert == XCD (round-robin dispatch)
    const int rem = bid >> 3;      // 0..175
    const int nt  = rem >> 2;      // 0..43
    const int mt  = rem & 3;

    __shared__ __align__(16) short Alds[2][BM * BK];   // 2 x 8 KB
    __shared__ __align__(16) short Blds[2][BN * BK];   // 2 x 8 KB

    const int tid = threadIdx.x;
    const int m0  = e * CAP + mt * BM;
    const int n0  = nt * BN;

    const unsigned short* Ab = abf + (size_t)m0 * KDIM;
    const unsigned short* Bb = wbt + ((size_t)e * NDIM + n0) * KDIM;

    f32x4 acc[4][4];
    #pragma unroll
    for (int i = 0; i < 4; ++i)
        #pragma unroll
        for (int j = 0; j < 4; ++j)
            acc[i][j] = (f32x4){0.f, 0.f, 0.f, 0.f};

    const int wave = tid >> 6;
    const int lane = tid & 63;
    const int wm = (wave >> 1) << 6;
    const int wn = (wave & 1) << 6;
    const int lr = lane & 15;
    const int lq = lane >> 4;

    // staging geometry: idx in [0,512) -> (row = idx>>2, 16B octet kq = idx&3)
    const int r0_ = tid >> 2;
    const int kq_ = tid & 3;

    // prologue: stage tile 0 into buf 0
    {
        gl2lds16(Ab + (size_t)r0_ * KDIM + kq_ * 8,        &Alds[0][tid * 8]);
        gl2lds16(Bb + (size_t)r0_ * KDIM + kq_ * 8,        &Blds[0][tid * 8]);
        gl2lds16(Ab + (size_t)(r0_ + 64) * KDIM + kq_ * 8, &Alds[0][(256 + tid) * 8]);
        gl2lds16(Bb + (size_t)(r0_ + 64) * KDIM + kq_ * 8, &Blds[0][(256 + tid) * 8]);
    }
    __syncthreads();

    int cur = 0;
    for (int k0 = 0; k0 < KDIM; k0 += BK) {
        // ---- issue next-tile stage into the other buffer (async, overlaps compute) ----
        if (k0 + BK < KDIM) {
            const int kn = k0 + BK;
            const int nb = cur ^ 1;
            gl2lds16(Ab + (size_t)r0_ * KDIM + kn + kq_ * 8,        &Alds[nb][tid * 8]);
            gl2lds16(Bb + (size_t)r0_ * KDIM + kn + kq_ * 8,        &Blds[nb][tid * 8]);
            gl2lds16(Ab + (size_t)(r0_ + 64) * KDIM + kn + kq_ * 8, &Alds[nb][(256 + tid) * 8]);
            gl2lds16(Bb + (size_t)(r0_ + 64) * KDIM + kn + kq_ * 8, &Blds[nb][(256 + tid) * 8]);
        }

        // ---- compute current buffer: 8 ds_read_b128 + 16 MFMA per wave ----
        bf16x8 af[4], bv[4];
        #pragma unroll
        for (int i = 0; i < 4; ++i)
            af[i] = *(const bf16x8*)&Alds[cur][(wm + i * 16 + lr) * BK + lq * 8];
        #pragma unroll
        for (int j = 0; j < 4; ++j)
            bv[j] = *(const bf16x8*)&Blds[cur][(wn + j * 16 + lr) * BK + lq * 8];
        #pragma unroll
        for (int i = 0; i < 4; ++i)
            #pragma unroll
            for (int j = 0; j < 4; ++j)
                acc[i][j] = __builtin_amdgcn_mfma_f32_16x16x32_bf16(af[i], bv[j], acc[i][j], 0, 0, 0);

        // one barrier per K-step: drains vmcnt (next tile landed) + lgkm, and
        // guarantees all waves are done reading buf[cur] before it is re-staged.
        __syncthreads();
        cur ^= 1;
    }

    const int orow0 = m0 + wm + lq * 4;
    const int ocol0 = n0 + wn + lr;
    #pragma unroll
    for (int i = 0; i < 4; ++i)
        #pragma unroll
        for (int r = 0; r < 4; ++r) {
            float* op = out + (size_t)(orow0 + i * 16 + r) * NDIM + ocol0;
            #pragma unroll
            for (int j = 0; j < 4; ++j)
                op[j * 16] = acc[i][j][r];
        }
}

// ---------------- Old pass 1: pack nibbles (mid-tier fallback) ----------------
__global__ __launch_bounds__(256)
void pack_kernel(const int* __restrict__ wq, const float* __restrict__ inp,
                 unsigned* __restrict__ pw, unsigned short* __restrict__ abf)
{
    const int bid = blockIdx.x;
    if (bid < PACK_BLOCKS) {
        const int e  = bid / (K8 * NBLK_N);
        const int r  = bid % (K8 * NBLK_N);
        const int k8 = r / NBLK_N;
        const int nb = r % NBLK_N;
        const int n  = nb * 256 + threadIdx.x;
        const int* src = wq + ((size_t)e * KDIM + k8 * 8) * NDIM + n;
        unsigned v = 0;
        #pragma unroll
        for (int j = 0; j < 8; ++j)
            v |= (unsigned)(src[(size_t)j * NDIM] & 15) << (4 * j);
        pw[((size_t)e * K8 + k8) * NDIM + n] = v;
    } else {
        const size_t t = (size_t)(bid - PACK_BLOCKS) * 256 + threadIdx.x;
        const float4* p = (const float4*)inp + t * 2;
        const float4 v0 = p[0], v1 = p[1];
        bf16x8 h;
        h[0] = f2bf(v0.x); h[1] = f2bf(v0.y); h[2] = f2bf(v0.z); h[3] = f2bf(v0.w);
        h[4] = f2bf(v1.x); h[5] = f2bf(v1.y); h[6] = f2bf(v1.z); h[7] = f2bf(v1.w);
        *((bf16x8*)abf + t) = h;
    }
}

// ---------------- Old pass 2: fused dequant GEMM (mid-tier fallback) ----------------
__global__ __launch_bounds__(256, 2)
void hqq_gemm2(const unsigned short* __restrict__ abf,
               const unsigned*       __restrict__ pw,
               const float*          __restrict__ sz,
               float*                __restrict__ out)
{
    const int bid = blockIdx.x;
    const int e   = bid / (MT * NT);
    const int rem = bid % (MT * NT);
    const int nt  = rem >> 2;
    const int mt  = rem & 3;

    __shared__ __align__(16) short Alds[BM * LDSS];
    __shared__ __align__(16) short Blds[BN * LDSS];

    const int tid = threadIdx.x;
    const int m0  = e * CAP + mt * BM;
    const int n0  = nt * BN;

    const int a_kq  = tid & 3;
    const int a_row = tid >> 2;
    const int b_n   = tid & 127;
    const int b_h   = tid >> 7;

    const unsigned short* Ab = abf + (size_t)m0 * KDIM;
    const unsigned*       Wb = pw  + (size_t)e * K8 * NDIM + n0 + b_n;
    const float*          SZb = sz + (size_t)e * NGRP * (NDIM * 2) + (size_t)(n0 + b_n) * 2;

    f32x4 acc[4][4];
    #pragma unroll
    for (int i = 0; i < 4; ++i)
        #pragma unroll
        for (int j = 0; j < 4; ++j)
            acc[i][j] = (f32x4){0.f, 0.f, 0.f, 0.f};

    const int wave = tid >> 6;
    const int lane = tid & 63;
    const int wm = (wave >> 1) << 6;
    const int wn = (wave & 1) << 6;
    const int lr = lane & 15;
    const int lq = lane >> 4;

    for (int k0 = 0; k0 < KDIM; k0 += BK) {
        const int g = k0 >> 6;
        #pragma unroll
        for (int p = 0; p < 2; ++p) {
            const int row = a_row + p * 64;
            const bf16x8 v = *(const bf16x8*)(Ab + (size_t)row * KDIM + k0 + a_kq * 8);
            *(bf16x8*)&Alds[row * LDSS + a_kq * 8] = v;
        }
        const float2 s2 = *(const float2*)(SZb + (size_t)g * (NDIM * 2));
        const float s  = s2.x;
        const float z8 = s2.y - 8.f * s2.x;
        const unsigned* wp = Wb + ((size_t)(k0 >> 3) + b_h * 2) * NDIM;
        const unsigned u0 = wp[0];
        const unsigned u1 = wp[NDIM];
        bf16x8 bb0, bb1;
        #pragma unroll
        for (int j = 0; j < 8; ++j) {
            bb0[j] = f2bf(fmaf((float)((u0 >> (4 * j)) & 15u), s, z8));
            bb1[j] = f2bf(fmaf((float)((u1 >> (4 * j)) & 15u), s, z8));
        }
        *(bf16x8*)&Blds[b_n * LDSS + b_h * 16]     = bb0;
        *(bf16x8*)&Blds[b_n * LDSS + b_h * 16 + 8] = bb1;

        __syncthreads();

        bf16x8 af[4], bfv[4];
        #pragma unroll
        for (int i = 0; i < 4; ++i)
            af[i] = *(const bf16x8*)&Alds[(wm + i * 16 + lr) * LDSS + lq * 8];
        #pragma unroll
        for (int j = 0; j < 4; ++j)
            bfv[j] = *(const bf16x8*)&Blds[(wn + j * 16 + lr) * LDSS + lq * 8];
        #pragma unroll
        for (int i = 0; i < 4; ++i)
            #pragma unroll
            for (int j = 0; j < 4; ++j)
                acc[i][j] = __builtin_amdgcn_mfma_f32_16x16x32_bf16(af[i], bfv[j], acc[i][j], 0, 0, 0);

        __syncthreads();
    }

    const int orow0 = m0 + wm + lq * 4;
    const int ocol0 = n0 + wn + lr;
    #pragma unroll
    for (int i = 0; i < 4; ++i)
        #pragma unroll
        for (int r = 0; r < 4; ++r) {
            float* op = out + (size_t)(orow0 + i * 16 + r) * NDIM + ocol0;
            #pragma unroll
            for (int j = 0; j < 4; ++j)
                op[j * 16] = acc[i][j][r];
        }
}

// ---------------- Fallback (no workspace) ----------------
__global__ __launch_bounds__(256, 2)
void hqq_gemm_fallback(const float* __restrict__ inp,
                       const int*   __restrict__ wq,
                       const float* __restrict__ sz,
                       float*       __restrict__ out)
{
    const int bid = blockIdx.x;
    const int e   = bid / (MT * NT);
    const int rem = bid % (MT * NT);
    const int nt  = rem >> 2;
    const int mt  = rem & 3;

    __shared__ __align__(16) short Alds[BM * LDSS];
    __shared__ __align__(16) short Blds[BN * LDSS];

    const int tid = threadIdx.x;
    const int m0  = e * CAP + mt * BM;
    const int n0  = nt * BN;

    const int a_kq  = tid & 7;
    const int a_row = tid >> 3;
    const int b_n   = tid & 127;
    const int b_h   = tid >> 7;

    const float* Ab  = inp + (size_t)m0 * KDIM;
    const int*   Wb  = wq  + (size_t)e * KDIM * NDIM + n0 + b_n;
    const float* SZb = sz  + (size_t)e * NGRP * (NDIM * 2) + (size_t)(n0 + b_n) * 2;

    f32x4 acc[4][4];
    #pragma unroll
    for (int i = 0; i < 4; ++i)
        #pragma unroll
        for (int j = 0; j < 4; ++j)
            acc[i][j] = (f32x4){0.f, 0.f, 0.f, 0.f};

    const int wave = tid >> 6;
    const int lane = tid & 63;
    const int wm = (wave >> 1) << 6;
    const int wn = (wave & 1) << 6;
    const int lr = lane & 15;
    const int lq = lane >> 4;

    for (int k0 = 0; k0 < KDIM; k0 += BK) {
        const int g = k0 >> 6;
        #pragma unroll
        for (int p = 0; p < 4; ++p) {
            const int row = a_row + p * 32;
            const float4 v = *(const float4*)(Ab + (size_t)row * KDIM + k0 + a_kq * 4);
            bf16x4 h;
            h[0] = f2bf(v.x); h[1] = f2bf(v.y); h[2] = f2bf(v.z); h[3] = f2bf(v.w);
            *(bf16x4*)&Alds[row * LDSS + a_kq * 4] = h;
        }
        const float2 s2 = *(const float2*)(SZb + (size_t)g * (NDIM * 2));
        const float s  = s2.x;
        const float z8 = s2.y - 8.f * s2.x;
        #pragma unroll
        for (int oo = 0; oo < 2; ++oo) {
            const int ko = b_h * 8 + oo * 16;
            const int* wp = Wb + (size_t)(k0 + ko) * NDIM;
            bf16x8 bb;
            #pragma unroll
            for (int j = 0; j < 8; ++j) {
                const float q = (float)wp[(size_t)j * NDIM];
                bb[j] = f2bf(fmaf(q, s, z8));
            }
            *(bf16x8*)&Blds[b_n * LDSS + ko] = bb;
        }
        __syncthreads();
        bf16x8 af[4], bfv[4];
        #pragma unroll
        for (int i = 0; i < 4; ++i)
            af[i] = *(const bf16x8*)&Alds[(wm + i * 16 + lr) * LDSS + lq * 8];
        #pragma unroll
        for (int j = 0; j < 4; ++j)
            bfv[j] = *(const bf16x8*)&Blds[(wn + j * 16 + lr) * LDSS + lq * 8];
        #pragma unroll
        for (int i = 0; i < 4; ++i)
            #pragma unroll
            for (int j = 0; j < 4; ++j)
                acc[i][j] = __builtin_amdgcn_mfma_f32_16x16x32_bf16(af[i], bfv[j], acc[i][j], 0, 0, 0);
        __syncthreads();
    }

    const int orow0 = m0 + wm + lq * 4;
    const int ocol0 = n0 + wn + lr;
    #pragma unroll
    for (int i = 0; i < 4; ++i)
        #pragma unroll
        for (int r = 0; r < 4; ++r) {
            float* op = out + (size_t)(orow0 + i * 16 + r) * NDIM + ocol0;
            #pragma unroll
            for (int j = 0; j < 4; ++j)
                op[j * 16] = acc[i][j][r];
        }
}

extern "C" void kernel_launch(void* const* d_in, const int* in_sizes, int n_in,
                              void* d_out, int out_size, void* d_ws, size_t ws_size,
                              hipStream_t stream) {
    const float* inp = (const float*)d_in[0];
    const int*   wq  = (const int*)d_in[2];
    const float* sz  = (const float*)d_in[3];
    float*       out = (float*)d_out;

    if (ws_size >= ABF_BYTES + WBT_BYTES) {
        unsigned short* abf = (unsigned short*)d_ws;
        unsigned short* wbt = (unsigned short*)((char*)d_ws + ABF_BYTES);
        dq_kernel<<<dim3(DQT_BLOCKS + ACV_BLOCKS), dim3(256), 0, stream>>>(wq, sz, inp, wbt, abf);
        hqq_gemm3<<<dim3(NE * MT * NT), dim3(256), 0, stream>>>(abf, wbt, out);
    } else if (ws_size >= PACKED_BYTES + ABF_BYTES) {
        unsigned*       pw  = (unsigned*)d_ws;
        unsigned short* abf = (unsigned short*)((char*)d_ws + PACKED_BYTES);
        pack_kernel<<<dim3(PACK_BLOCKS + ACV_BLOCKS), dim3(256), 0, stream>>>(wq, inp, pw, abf);
        hqq_gemm2<<<dim3(NE * MT * NT), dim3(256), 0, stream>>>(abf, pw, sz, out);
    } else {
        hqq_gemm_fallback<<<dim3(NE * MT * NT), dim3(256), 0, stream>>>(inp, wq, sz, out);
    }
}

// Round 6
// 692.641 us; speedup vs baseline: 1.2007x; 1.0097x over previous
//
#include <hip/hip_runtime.h>

// Problem constants (from reference)
#define NE    8
#define KDIM  2048
#define NDIM  5632
#define NTOK  4096
#define CAP   512      // tokens per expert (balanced routing, = NTOK/NE)
#define NGRP  32       // KDIM / GROUP_SIZE(64)
#define BM    128
#define BN    128
#define BK    32
#define MT    4        // CAP / BM
#define NT    44       // NDIM / BN
#define LDSS  40       // padded LDS row stride (old path)

#define K8      (KDIM / 8)                                  // 256 packed octet-rows
#define NBLK_N  (NDIM / 256)                                // 22
#define PACK_BLOCKS (NE * K8 * NBLK_N)                      // 45056
#define ACV_BLOCKS  (NTOK * KDIM / (8 * 256))               // 4096
#define PACKED_BYTES ((size_t)NE * K8 * NDIM * 4)           // 46,137,344
#define ABF_BYTES    ((size_t)NTOK * KDIM * 2)              // 16,777,216
#define WBT_BYTES    ((size_t)NE * NDIM * KDIM * 2)         // 184,549,376

// dequant-transpose pass geometry: [128 k x 128 n] tile per block
#define KT_DQ (KDIM / 128)                                  // 16
#define NT_DQ (NDIM / 128)                                  // 44
#define DQT_BLOCKS (NE * KT_DQ * NT_DQ)                     // 5632

typedef __attribute__((ext_vector_type(8))) short bf16x8;
typedef __attribute__((ext_vector_type(4))) short bf16x4;
typedef __attribute__((ext_vector_type(4))) float f32x4;

// fp32 -> bf16 round-to-nearest-even (finite inputs only)
static __device__ __forceinline__ short f2bf(float f) {
    union { float f; unsigned u; } x; x.f = f;
    unsigned r = (x.u + 0x7fffu + ((x.u >> 16) & 1u)) >> 16;
    return (short)r;
}

// async global->LDS, 16B per lane. LDS dest must be wave-uniform base + lane*16.
static __device__ __forceinline__ void gl2lds16(const unsigned short* g, short* l) {
    __builtin_amdgcn_global_load_lds(
        (const __attribute__((address_space(1))) unsigned int*)g,
        (__attribute__((address_space(3))) unsigned int*)l, 16, 0, 0);
}

// ---------------- Pass 1: dequant int32 codes -> bf16 B^T [E][N][K] via LDS transpose ----
// Reads:  [128k x 128n] int tile; per wave-instr 2 rows x 512 B contiguous (full lines).
// Writes: per wave-instr 8 n-rows x 128 B contiguous runs (full lines) -> no write amp.
// LDS: [n][k] bf16 tile, 16B slots XOR-swizzled by (n&15) for bank spread both phases.
__global__ __launch_bounds__(256)
void dq_kernel(const int* __restrict__ wq, const float* __restrict__ sz,
               const float* __restrict__ inp,
               unsigned short* __restrict__ wbt, unsigned short* __restrict__ abf)
{
    const int bid = blockIdx.x;
    if (bid < DQT_BLOCKS) {
        const int e  = bid / (KT_DQ * NT_DQ);
        const int r  = bid % (KT_DQ * NT_DQ);
        const int kt = r / NT_DQ;
        const int ntb = r % NT_DQ;
        const int k0 = kt * 128;
        const int n0 = ntb * 128;
        const int t  = threadIdx.x;

        __shared__ __align__(16) short T[128 * 128];   // 32 KB

        // ---- read phase: thread owns 4 ints (n) x 16 rows (k) ----
        const int col  = t & 31;          // 16B column: ints [col*4, col*4+4)
        const int band = t >> 5;          // 0..7 -> rows band*16 .. band*16+15
        const int g    = (k0 >> 6) + (band >> 2);   // scale group (uniform per thread)

        float s_[4], z_[4];
        #pragma unroll
        for (int j = 0; j < 4; ++j) {
            const int n = n0 + col * 4 + j;
            const float2 s2 = *(const float2*)(sz + (((size_t)e * NGRP + g) * NDIM + n) * 2);
            s_[j] = s2.x;
            z_[j] = s2.y - 8.f * s2.x;    // w = q*s + (z - 8s)
        }

        const int* src = wq + ((size_t)e * KDIM + k0 + band * 16) * NDIM + n0 + col * 4;

        #pragma unroll
        for (int p4 = 0; p4 < 4; ++p4) {
            // 4 consecutive k-rows, 4 n each -> 4x4 micro-transpose
            int4 v0 = *(const int4*)(src + (size_t)(p4 * 4 + 0) * NDIM);
            int4 v1 = *(const int4*)(src + (size_t)(p4 * 4 + 1) * NDIM);
            int4 v2 = *(const int4*)(src + (size_t)(p4 * 4 + 2) * NDIM);
            int4 v3 = *(const int4*)(src + (size_t)(p4 * 4 + 3) * NDIM);
            const int kb = band * 16 + p4 * 4;
            const int slotbase = kb >> 3;          // 16B slot of this quad
            const int halfoff  = (kb & 7);         // 0 or 4 shorts within slot

            #pragma unroll
            for (int j = 0; j < 4; ++j) {
                const int q0 = (j == 0) ? v0.x : (j == 1) ? v0.y : (j == 2) ? v0.z : v0.w;
                const int q1 = (j == 0) ? v1.x : (j == 1) ? v1.y : (j == 2) ? v1.z : v1.w;
                const int q2 = (j == 0) ? v2.x : (j == 1) ? v2.y : (j == 2) ? v2.z : v2.w;
                const int q3 = (j == 0) ? v3.x : (j == 1) ? v3.y : (j == 2) ? v3.z : v3.w;
                bf16x4 quad;
                quad[0] = f2bf(fmaf((float)q0, s_[j], z_[j]));
                quad[1] = f2bf(fmaf((float)q1, s_[j], z_[j]));
                quad[2] = f2bf(fmaf((float)q2, s_[j], z_[j]));
                quad[3] = f2bf(fmaf((float)q3, s_[j], z_[j]));
                const int n_l = col * 4 + j;
                const int addr = n_l * 128 + ((slotbase ^ (n_l & 15)) << 3) + halfoff;
                *(bf16x4*)&T[addr] = quad;
            }
        }

        __syncthreads();

        // ---- write phase: 8 lanes per n-row -> 128B contiguous runs ----
        const int wc = t & 7;             // slot within half-row
        const int wn = t >> 3;            // 0..31
        #pragma unroll
        for (int p = 0; p < 4; ++p) {
            const int n_l = wn + p * 32;
            const int x = n_l & 15;
            unsigned short* dst = wbt + ((size_t)e * NDIM + n0 + n_l) * KDIM + k0;
            const bf16x8 r0 = *(const bf16x8*)&T[n_l * 128 + ((wc ^ x) << 3)];
            const bf16x8 r1 = *(const bf16x8*)&T[n_l * 128 + (((wc + 8) ^ x) << 3)];
            *(bf16x8*)(dst + wc * 8) = r0;
            *(bf16x8*)(dst + (wc + 8) * 8) = r1;
        }
    } else {
        // A fp32 -> bf16, 8 elems/thread
        const size_t t = (size_t)(bid - DQT_BLOCKS) * 256 + threadIdx.x;
        const float4* p = (const float4*)inp + t * 2;
        const float4 v0 = p[0], v1 = p[1];
        bf16x8 h;
        h[0] = f2bf(v0.x); h[1] = f2bf(v0.y); h[2] = f2bf(v0.z); h[3] = f2bf(v0.w);
        h[4] = f2bf(v1.x); h[5] = f2bf(v1.y); h[6] = f2bf(v1.z); h[7] = f2bf(v1.w);
        *((bf16x8*)abf + t) = h;
    }
}

// ---------------- Pass 2: bf16 grouped GEMM, 3-buffer 2-deep pipeline, counted vmcnt ----
// T3/T4: prefetch 2 K-tiles ahead into rotating LDS buffers; raw s_barrier with
// s_waitcnt vmcnt(4) (one tile = 4 global_load_lds per wave stays in flight across
// the barrier). Never drains to 0 in the main loop -> per-step cost is compute,
// not load latency. Hazards: stage(t+2) after the top barrier (its target buffer
// ≡ t-1 mod 3, all readers past); asm "memory" clobber + sched_barrier(0) pin the
// ds_reads below the waitcnt+barrier; per-wave vmcnt + barrier => whole tile landed.
__global__ __launch_bounds__(256, 3)
void hqq_gemm3(const unsigned short* __restrict__ abf,
               const unsigned short* __restrict__ wbt,
               float* __restrict__ out)
{
    const int bid = blockIdx.x;
    const int e   = bid & 7;       // expert == XCD (round-robin dispatch)
    const int rem = bid >> 3;      // 0..175
    const int nt  = rem >> 2;      // 0..43
    const int mt  = rem & 3;

    __shared__ __align__(16) short Alds[3][BM * BK];   // 3 x 8 KB
    __shared__ __align__(16) short Blds[3][BN * BK];   // 3 x 8 KB

    const int tid = threadIdx.x;
    const int m0  = e * CAP + mt * BM;
    const int n0  = nt * BN;

    const unsigned short* Ab = abf + (size_t)m0 * KDIM;
    const unsigned short* Bb = wbt + ((size_t)e * NDIM + n0) * KDIM;

    f32x4 acc[4][4];
    #pragma unroll
    for (int i = 0; i < 4; ++i)
        #pragma unroll
        for (int j = 0; j < 4; ++j)
            acc[i][j] = (f32x4){0.f, 0.f, 0.f, 0.f};

    const int wave = tid >> 6;
    const int lane = tid & 63;
    const int wm = (wave >> 1) << 6;
    const int wn = (wave & 1) << 6;
    const int lr = lane & 15;
    const int lq = lane >> 4;

    // staging geometry: idx in [0,512) -> (row = idx>>2, 16B octet kq = idx&3)
    const int r0_ = tid >> 2;
    const int kq_ = tid & 3;

    // 4 global_load_lds per wave per tile (A p0,p1 + B p0,p1)
#define STAGE3(kk, Adst, Bdst)                                                       \
    do {                                                                             \
        gl2lds16(Ab + (size_t)r0_ * KDIM + (kk) + kq_ * 8,        (Adst) + tid * 8); \
        gl2lds16(Bb + (size_t)r0_ * KDIM + (kk) + kq_ * 8,        (Bdst) + tid * 8); \
        gl2lds16(Ab + (size_t)(r0_ + 64) * KDIM + (kk) + kq_ * 8, (Adst) + (256 + tid) * 8); \
        gl2lds16(Bb + (size_t)(r0_ + 64) * KDIM + (kk) + kq_ * 8, (Bdst) + (256 + tid) * 8); \
    } while (0)

    short* Ac = &Alds[0][0]; short* An = &Alds[1][0]; short* Af = &Alds[2][0];
    short* Bc = &Blds[0][0]; short* Bn = &Blds[1][0]; short* Bf = &Blds[2][0];

    // prologue: tiles 0 and 1 in flight (8 outstanding loads per wave)
    STAGE3(0,  Ac, Bc);
    STAGE3(BK, An, Bn);

    for (int k0 = 0; k0 < KDIM; k0 += BK) {
        // wait current tile landed; keep next tile's 4 loads in flight
        if (k0 + BK < KDIM) {
            asm volatile("s_waitcnt vmcnt(4)" ::: "memory");
        } else {
            asm volatile("s_waitcnt vmcnt(0)" ::: "memory");
        }
        __builtin_amdgcn_s_barrier();
        asm volatile("" ::: "memory");
        __builtin_amdgcn_sched_barrier(0);

        // prefetch tile t+2 into the free buffer (readers of its old contents are past)
        if (k0 + 2 * BK < KDIM)
            STAGE3(k0 + 2 * BK, Af, Bf);

        // ---- compute current buffer: 8 ds_read_b128 + 16 MFMA per wave ----
        bf16x8 af[4], bv[4];
        #pragma unroll
        for (int i = 0; i < 4; ++i)
            af[i] = *(const bf16x8*)&Ac[(wm + i * 16 + lr) * BK + lq * 8];
        #pragma unroll
        for (int j = 0; j < 4; ++j)
            bv[j] = *(const bf16x8*)&Bc[(wn + j * 16 + lr) * BK + lq * 8];
        #pragma unroll
        for (int i = 0; i < 4; ++i)
            #pragma unroll
            for (int j = 0; j < 4; ++j)
                acc[i][j] = __builtin_amdgcn_mfma_f32_16x16x32_bf16(af[i], bv[j], acc[i][j], 0, 0, 0);

        // rotate buffers: cur <- next, next <- far, far <- old cur
        short* tA = Ac; Ac = An; An = Af; Af = tA;
        short* tB = Bc; Bc = Bn; Bn = Bf; Bf = tB;
    }
#undef STAGE3

    const int orow0 = m0 + wm + lq * 4;
    const int ocol0 = n0 + wn + lr;
    #pragma unroll
    for (int i = 0; i < 4; ++i)
        #pragma unroll
        for (int r = 0; r < 4; ++r) {
            float* op = out + (size_t)(orow0 + i * 16 + r) * NDIM + ocol0;
            #pragma unroll
            for (int j = 0; j < 4; ++j)
                op[j * 16] = acc[i][j][r];
        }
}

// ---------------- Old pass 1: pack nibbles (mid-tier fallback) ----------------
__global__ __launch_bounds__(256)
void pack_kernel(const int* __restrict__ wq, const float* __restrict__ inp,
                 unsigned* __restrict__ pw, unsigned short* __restrict__ abf)
{
    const int bid = blockIdx.x;
    if (bid < PACK_BLOCKS) {
        const int e  = bid / (K8 * NBLK_N);
        const int r  = bid % (K8 * NBLK_N);
        const int k8 = r / NBLK_N;
        const int nb = r % NBLK_N;
        const int n  = nb * 256 + threadIdx.x;
        const int* src = wq + ((size_t)e * KDIM + k8 * 8) * NDIM + n;
        unsigned v = 0;
        #pragma unroll
        for (int j = 0; j < 8; ++j)
            v |= (unsigned)(src[(size_t)j * NDIM] & 15) << (4 * j);
        pw[((size_t)e * K8 + k8) * NDIM + n] = v;
    } else {
        const size_t t = (size_t)(bid - PACK_BLOCKS) * 256 + threadIdx.x;
        const float4* p = (const float4*)inp + t * 2;
        const float4 v0 = p[0], v1 = p[1];
        bf16x8 h;
        h[0] = f2bf(v0.x); h[1] = f2bf(v0.y); h[2] = f2bf(v0.z); h[3] = f2bf(v0.w);
        h[4] = f2bf(v1.x); h[5] = f2bf(v1.y); h[6] = f2bf(v1.z); h[7] = f2bf(v1.w);
        *((bf16x8*)abf + t) = h;
    }
}

// ---------------- Old pass 2: fused dequant GEMM (mid-tier fallback) ----------------
__global__ __launch_bounds__(256, 2)
void hqq_gemm2(const unsigned short* __restrict__ abf,
               const unsigned*       __restrict__ pw,
               const float*          __restrict__ sz,
               float*                __restrict__ out)
{
    const int bid = blockIdx.x;
    const int e   = bid / (MT * NT);
    const int rem = bid % (MT * NT);
    const int nt  = rem >> 2;
    const int mt  = rem & 3;

    __shared__ __align__(16) short Alds[BM * LDSS];
    __shared__ __align__(16) short Blds[BN * LDSS];

    const int tid = threadIdx.x;
    const int m0  = e * CAP + mt * BM;
    const int n0  = nt * BN;

    const int a_kq  = tid & 3;
    const int a_row = tid >> 2;
    const int b_n   = tid & 127;
    const int b_h   = tid >> 7;

    const unsigned short* Ab = abf + (size_t)m0 * KDIM;
    const unsigned*       Wb = pw  + (size_t)e * K8 * NDIM + n0 + b_n;
    const float*          SZb = sz + (size_t)e * NGRP * (NDIM * 2) + (size_t)(n0 + b_n) * 2;

    f32x4 acc[4][4];
    #pragma unroll
    for (int i = 0; i < 4; ++i)
        #pragma unroll
        for (int j = 0; j < 4; ++j)
            acc[i][j] = (f32x4){0.f, 0.f, 0.f, 0.f};

    const int wave = tid >> 6;
    const int lane = tid & 63;
    const int wm = (wave >> 1) << 6;
    const int wn = (wave & 1) << 6;
    const int lr = lane & 15;
    const int lq = lane >> 4;

    for (int k0 = 0; k0 < KDIM; k0 += BK) {
        const int g = k0 >> 6;
        #pragma unroll
        for (int p = 0; p < 2; ++p) {
            const int row = a_row + p * 64;
            const bf16x8 v = *(const bf16x8*)(Ab + (size_t)row * KDIM + k0 + a_kq * 8);
            *(bf16x8*)&Alds[row * LDSS + a_kq * 8] = v;
        }
        const float2 s2 = *(const float2*)(SZb + (size_t)g * (NDIM * 2));
        const float s  = s2.x;
        const float z8 = s2.y - 8.f * s2.x;
        const unsigned* wp = Wb + ((size_t)(k0 >> 3) + b_h * 2) * NDIM;
        const unsigned u0 = wp[0];
        const unsigned u1 = wp[NDIM];
        bf16x8 bb0, bb1;
        #pragma unroll
        for (int j = 0; j < 8; ++j) {
            bb0[j] = f2bf(fmaf((float)((u0 >> (4 * j)) & 15u), s, z8));
            bb1[j] = f2bf(fmaf((float)((u1 >> (4 * j)) & 15u), s, z8));
        }
        *(bf16x8*)&Blds[b_n * LDSS + b_h * 16]     = bb0;
        *(bf16x8*)&Blds[b_n * LDSS + b_h * 16 + 8] = bb1;

        __syncthreads();

        bf16x8 af[4], bfv[4];
        #pragma unroll
        for (int i = 0; i < 4; ++i)
            af[i] = *(const bf16x8*)&Alds[(wm + i * 16 + lr) * LDSS + lq * 8];
        #pragma unroll
        for (int j = 0; j < 4; ++j)
            bfv[j] = *(const bf16x8*)&Blds[(wn + j * 16 + lr) * LDSS + lq * 8];
        #pragma unroll
        for (int i = 0; i < 4; ++i)
            #pragma unroll
            for (int j = 0; j < 4; ++j)
                acc[i][j] = __builtin_amdgcn_mfma_f32_16x16x32_bf16(af[i], bfv[j], acc[i][j], 0, 0, 0);

        __syncthreads();
    }

    const int orow0 = m0 + wm + lq * 4;
    const int ocol0 = n0 + wn + lr;
    #pragma unroll
    for (int i = 0; i < 4; ++i)
        #pragma unroll
        for (int r = 0; r < 4; ++r) {
            float* op = out + (size_t)(orow0 + i * 16 + r) * NDIM + ocol0;
            #pragma unroll
            for (int j = 0; j < 4; ++j)
                op[j * 16] = acc[i][j][r];
        }
}

// ---------------- Fallback (no workspace) ----------------
__global__ __launch_bounds__(256, 2)
void hqq_gemm_fallback(const float* __restrict__ inp,
                       const int*   __restrict__ wq,
                       const float* __restrict__ sz,
                       float*       __restrict__ out)
{
    const int bid = blockIdx.x;
    const int e   = bid / (MT * NT);
    const int rem = bid % (MT * NT);
    const int nt  = rem >> 2;
    const int mt  = rem & 3;

    __shared__ __align__(16) short Alds[BM * LDSS];
    __shared__ __align__(16) short Blds[BN * LDSS];

    const int tid = threadIdx.x;
    const int m0  = e * CAP + mt * BM;
    const int n0  = nt * BN;

    const int a_kq  = tid & 7;
    const int a_row = tid >> 3;
    const int b_n   = tid & 127;
    const int b_h   = tid >> 7;

    const float* Ab  = inp + (size_t)m0 * KDIM;
    const int*   Wb  = wq  + (size_t)e * KDIM * NDIM + n0 + b_n;
    const float* SZb = sz  + (size_t)e * NGRP * (NDIM * 2) + (size_t)(n0 + b_n) * 2;

    f32x4 acc[4][4];
    #pragma unroll
    for (int i = 0; i < 4; ++i)
        #pragma unroll
        for (int j = 0; j < 4; ++j)
            acc[i][j] = (f32x4){0.f, 0.f, 0.f, 0.f};

    const int wave = tid >> 6;
    const int lane = tid & 63;
    const int wm = (wave >> 1) << 6;
    const int wn = (wave & 1) << 6;
    const int lr = lane & 15;
    const int lq = lane >> 4;

    for (int k0 = 0; k0 < KDIM; k0 += BK) {
        const int g = k0 >> 6;
        #pragma unroll
        for (int p = 0; p < 4; ++p) {
            const int row = a_row + p * 32;
            const float4 v = *(const float4*)(Ab + (size_t)row * KDIM + k0 + a_kq * 4);
            bf16x4 h;
            h[0] = f2bf(v.x); h[1] = f2bf(v.y); h[2] = f2bf(v.z); h[3] = f2bf(v.w);
            *(bf16x4*)&Alds[row * LDSS + a_kq * 4] = h;
        }
        const float2 s2 = *(const float2*)(SZb + (size_t)g * (NDIM * 2));
        const float s  = s2.x;
        const float z8 = s2.y - 8.f * s2.x;
        #pragma unroll
        for (int oo = 0; oo < 2; ++oo) {
            const int ko = b_h * 8 + oo * 16;
            const int* wp = Wb + (size_t)(k0 + ko) * NDIM;
            bf16x8 bb;
            #pragma unroll
            for (int j = 0; j < 8; ++j) {
                const float q = (float)wp[(size_t)j * NDIM];
                bb[j] = f2bf(fmaf(q, s, z8));
            }
            *(bf16x8*)&Blds[b_n * LDSS + ko] = bb;
        }
        __syncthreads();
        bf16x8 af[4], bfv[4];
        #pragma unroll
        for (int i = 0; i < 4; ++i)
            af[i] = *(const bf16x8*)&Alds[(wm + i * 16 + lr) * LDSS + lq * 8];
        #pragma unroll
        for (int j = 0; j < 4; ++j)
            bfv[j] = *(const bf16x8*)&Blds[(wn + j * 16 + lr) * LDSS + lq * 8];
        #pragma unroll
        for (int i = 0; i < 4; ++i)
            #pragma unroll
            for (int j = 0; j < 4; ++j)
                acc[i][j] = __builtin_amdgcn_mfma_f32_16x16x32_bf16(af[i], bfv[j], acc[i][j], 0, 0, 0);
        __syncthreads();
    }

    const int orow0 = m0 + wm + lq * 4;
    const int ocol0 = n0 + wn + lr;
    #pragma unroll
    for (int i = 0; i < 4; ++i)
        #pragma unroll
        for (int r = 0; r < 4; ++r) {
            float* op = out + (size_t)(orow0 + i * 16 + r) * NDIM + ocol0;
            #pragma unroll
            for (int j = 0; j < 4; ++j)
                op[j * 16] = acc[i][j][r];
        }
}

extern "C" void kernel_launch(void* const* d_in, const int* in_sizes, int n_in,
                              void* d_out, int out_size, void* d_ws, size_t ws_size,
                              hipStream_t stream) {
    const float* inp = (const float*)d_in[0];
    const int*   wq  = (const int*)d_in[2];
    const float* sz  = (const float*)d_in[3];
    float*       out = (float*)d_out;

    if (ws_size >= ABF_BYTES + WBT_BYTES) {
        unsigned short* abf = (unsigned short*)d_ws;
        unsigned short* wbt = (unsigned short*)((char*)d_ws + ABF_BYTES);
        dq_kernel<<<dim3(DQT_BLOCKS + ACV_BLOCKS), dim3(256), 0, stream>>>(wq, sz, inp, wbt, abf);
        hqq_gemm3<<<dim3(NE * MT * NT), dim3(256), 0, stream>>>(abf, wbt, out);
    } else if (ws_size >= PACKED_BYTES + ABF_BYTES) {
        unsigned*       pw  = (unsigned*)d_ws;
        unsigned short* abf = (unsigned short*)((char*)d_ws + PACKED_BYTES);
        pack_kernel<<<dim3(PACK_BLOCKS + ACV_BLOCKS), dim3(256), 0, stream>>>(wq, inp, pw, abf);
        hqq_gemm2<<<dim3(NE * MT * NT), dim3(256), 0, stream>>>(abf, pw, sz, out);
    } else {
        hqq_gemm_fallback<<<dim3(NE * MT * NT), dim3(256), 0, stream>>>(inp, wq, sz, out);
    }
}